// Round 14
// baseline (3092.766 us; speedup 1.0000x reference)
//
#include <hip/hip_runtime.h>
#include <hip/hip_bf16.h>

#define NFEAT 256
#define HID 64
#define NCLASS 40
#define NUM_LAYERS 3

// ---------------------------------------------------------------------------
// lin1: h = relu(x @ w1.T + b1)   x:[N,256] w1:[64,256] -> h:[N,64]
// ---------------------------------------------------------------------------
__global__ __launch_bounds__(256) void k_lin1(
    const float* __restrict__ x, const float* __restrict__ w1,
    const float* __restrict__ b1, float* __restrict__ h, int n_nodes)
{
    __shared__ float xs[8][NFEAT];     // 8 KB
    __shared__ float part[4][8][HID];  // 8 KB
    const int tid  = threadIdx.x;
    const int wave = tid >> 6;
    const int lane = tid & 63;

    float wreg[64];
#pragma unroll
    for (int k = 0; k < 64; k += 4) {
        float4 v = *reinterpret_cast<const float4*>(&w1[lane * NFEAT + wave * 64 + k]);
        wreg[k] = v.x; wreg[k + 1] = v.y; wreg[k + 2] = v.z; wreg[k + 3] = v.w;
    }

    const int nbatch = (n_nodes + 7) >> 3;
    for (int batch = blockIdx.x; batch < nbatch; batch += gridDim.x) {
        const int n0 = batch * 8;
        {
            const float4* xg = reinterpret_cast<const float4*>(x + (size_t)n0 * NFEAT);
            float4* xsv = reinterpret_cast<float4*>(&xs[0][0]);
#pragma unroll
            for (int i = 0; i < 2; ++i) {
                int idx  = tid + i * 256;
                int node = n0 + (idx >> 6);
                xsv[idx] = (node < n_nodes) ? xg[idx] : make_float4(0.f, 0.f, 0.f, 0.f);
            }
        }
        __syncthreads();
        for (int nl = 0; nl < 8; ++nl) {
            const float4* xrow = reinterpret_cast<const float4*>(&xs[nl][wave * 64]);
            float a0 = 0.f, a1 = 0.f, a2 = 0.f, a3 = 0.f;
#pragma unroll
            for (int kq = 0; kq < 16; ++kq) {
                float4 v = xrow[kq];
                a0 = fmaf(v.x, wreg[4 * kq + 0], a0);
                a1 = fmaf(v.y, wreg[4 * kq + 1], a1);
                a2 = fmaf(v.z, wreg[4 * kq + 2], a2);
                a3 = fmaf(v.w, wreg[4 * kq + 3], a3);
            }
            part[wave][nl][lane] = (a0 + a1) + (a2 + a3);
        }
        __syncthreads();
#pragma unroll
        for (int i = 0; i < 2; ++i) {
            int o = tid + i * 256;
            int nl = o >> 6, j = o & 63;
            int node = n0 + nl;
            if (node < n_nodes) {
                float v = part[0][nl][j] + part[1][nl][j] + part[2][nl][j] + part[3][nl][j]
                          + b1[j];
                h[(size_t)node * HID + j] = fmaxf(v, 0.f);
            }
        }
        __syncthreads();
    }
}

// ---------------------------------------------------------------------------
// CSR build: histogram of dst, exclusive scan, fill col_src  (int32 inputs)
// ---------------------------------------------------------------------------
__global__ void k_hist(const int* __restrict__ ei, int* __restrict__ cnt, int E)
{
    int i = blockIdx.x * blockDim.x + threadIdx.x;
    if (i < E) atomicAdd(&cnt[ei[E + i]], 1);
}

#define SCAN_C 2048
__global__ __launch_bounds__(512) void k_scan1(const int* __restrict__ cnt,
                                               int* __restrict__ btot, int n)
{
    __shared__ int sd[512];
    int b = blockIdx.x, t = threadIdx.x;
    int base = b * SCAN_C + t * 4;
    int s = 0;
#pragma unroll
    for (int i = 0; i < 4; ++i) { int idx = base + i; if (idx < n) s += cnt[idx]; }
    sd[t] = s; __syncthreads();
    for (int off = 256; off > 0; off >>= 1) {
        if (t < off) sd[t] += sd[t + off];
        __syncthreads();
    }
    if (t == 0) btot[b] = sd[0];
}

__global__ __launch_bounds__(1024) void k_scan2(int* __restrict__ btot, int nb)
{
    __shared__ int sd[1024];
    int t = threadIdx.x;
    int v = (t < nb) ? btot[t] : 0;
    sd[t] = v; __syncthreads();
    for (int off = 1; off < 1024; off <<= 1) {
        int x = sd[t];
        int add = (t >= off) ? sd[t - off] : 0;
        __syncthreads();
        sd[t] = x + add;
        __syncthreads();
    }
    if (t < nb) btot[t] = sd[t] - v;  // exclusive
}

__global__ __launch_bounds__(512) void k_scan3(const int* __restrict__ cnt,
                                               const int* __restrict__ btot,
                                               int* __restrict__ row_ptr,
                                               int* __restrict__ cursor, int n)
{
    __shared__ int sth[512];
    int b = blockIdx.x, t = threadIdx.x;
    int base = b * SCAN_C + t * 4;
    int v[4]; int s = 0;
#pragma unroll
    for (int i = 0; i < 4; ++i) { int idx = base + i; v[i] = (idx < n) ? cnt[idx] : 0; s += v[i]; }
    sth[t] = s; __syncthreads();
    int mine = s;
    for (int off = 1; off < 512; off <<= 1) {
        int x = sth[t];
        int add = (t >= off) ? sth[t - off] : 0;
        __syncthreads();
        sth[t] = x + add;
        __syncthreads();
    }
    int carry = btot[b] + (sth[t] - mine);
#pragma unroll
    for (int i = 0; i < 4; ++i) {
        int idx = base + i;
        if (idx < n) {
            row_ptr[idx] = carry;
            cursor[idx]  = carry;
            carry += v[i];
            if (idx == n - 1) row_ptr[n] = carry;  // = E
        }
    }
}

__global__ void k_fill(const int* __restrict__ ei, int* __restrict__ cursor,
                       int* __restrict__ col_src, int E)
{
    int i = blockIdx.x * blockDim.x + threadIdx.x;
    if (i < E) {
        int dst = ei[E + i];
        int p = atomicAdd(&cursor[dst], 1);
        col_src[p] = ei[i];
    }
}

// ---------------------------------------------------------------------------
// aggregation: ah[n] = sum_{e: dst=n} h[src[e]]   (wave per node, lane = feat)
// ---------------------------------------------------------------------------
__global__ __launch_bounds__(256) void k_agg(
    const float* __restrict__ h, const int* __restrict__ row_ptr,
    const int* __restrict__ col_src, float* __restrict__ ah, int n_nodes)
{
    int wid    = (blockIdx.x * blockDim.x + threadIdx.x) >> 6;
    int lane   = threadIdx.x & 63;
    int nwaves = (gridDim.x * blockDim.x) >> 6;
    for (int node = wid; node < n_nodes; node += nwaves) {
        int e0 = row_ptr[node], e1 = row_ptr[node + 1];
        float acc = 0.f;
        int e = e0;
        for (; e + 4 <= e1; e += 4) {
            int s0 = col_src[e], s1 = col_src[e + 1], s2 = col_src[e + 2], s3 = col_src[e + 3];
            float v0 = h[(size_t)s0 * HID + lane];
            float v1 = h[(size_t)s1 * HID + lane];
            float v2 = h[(size_t)s2 * HID + lane];
            float v3 = h[(size_t)s3 * HID + lane];
            acc += (v0 + v1) + (v2 + v3);
        }
        for (; e < e1; ++e) acc += h[(size_t)col_src[e] * HID + lane];
        ah[(size_t)node * HID + lane] = acc;
    }
}

// ---------------------------------------------------------------------------
// Wic[l][j][k] = sum_m w_ih[j][m] * gg_w[l][k][m]
// (agg = segsum(h) @ gg_w[l]  =>  gi = segsum(h) @ (gg_w[l] @ w_ih.T))
// ---------------------------------------------------------------------------
__global__ void k_wic(const float* __restrict__ gg_w, const float* __restrict__ w_ih,
                      float* __restrict__ Wic)
{
    int idx = blockIdx.x * blockDim.x + threadIdx.x;
    if (idx < NUM_LAYERS * 192 * 64) {
        int l = idx / (192 * 64);
        int j = (idx / 64) % 192;
        int k = idx % 64;
        const float* gw = gg_w + ((size_t)l * 64 + k) * 64;
        const float* wi = w_ih + (size_t)j * 64;
        float acc = 0.f;
#pragma unroll 4
        for (int m = 0; m < 64; ++m) acc = fmaf(wi[m], gw[m], acc);
        Wic[idx] = acc;
    }
}

// ---------------------------------------------------------------------------
// fused GRU v7 — the session synthesis:
//  - thread = node; ar[64]+hr[64] in VGPRs. __launch_bounds__(256, 1) is the
//    ONLY config that verifiably raised the VGPR cap to 256 (r9). 96 KB LDS
//    forces 1 block/CU anyway, so the min-blocks=1 promise costs nothing.
//  - weights in LDS (96 KB, r3-verified), read at LOOP-CONSTANT uniform
//    addresses -> broadcast ds_read_b128, conflict-free, vector-mem pipe.
//    (r13 lesson: threadIdx-derived weight indices compile to per-lane
//    global loads — LLVM divergence analysis can't see wave-uniformity.
//    r9 lesson: s_load streaming dies of SGPR pressure + latency at low
//    occupancy. Loop-constant LDS reads dodge both.)
//  - j-tile 4; acc[4][6] static; hold4 re-read from global (rule #20).
//  - no gi round-trip: traffic = read ah+h, write h = 153 MB/layer.
// Tripwire: VGPR_Count <= 128 in profile => allocator spilled ar/hr again =>
// abandon fused GRU permanently, return to r8 two-pass.
// ---------------------------------------------------------------------------
#define G7_BLK 256
__global__ __launch_bounds__(G7_BLK, 1) void k_gru7(
    const float* __restrict__ ah, float* __restrict__ h,
    const float* __restrict__ Wic, const float* __restrict__ whh,
    const float* __restrict__ b_ih, const float* __restrict__ b_hh, int n_nodes)
{
    __shared__ float wi[192 * 64];  // 48 KB
    __shared__ float wh[192 * 64];  // 48 KB
    const int tid = threadIdx.x;

    // stage weights once per block (3072 float4 each, coalesced)
    {
        const float4* s1 = reinterpret_cast<const float4*>(Wic);
        const float4* s2 = reinterpret_cast<const float4*>(whh);
        float4* d1 = reinterpret_cast<float4*>(wi);
        float4* d2 = reinterpret_cast<float4*>(wh);
        for (int i = tid; i < 3072; i += G7_BLK) { d1[i] = s1[i]; d2[i] = s2[i]; }
    }
    __syncthreads();

    const int node = blockIdx.x * G7_BLK + tid;
    if (node >= n_nodes) return;  // after barrier: safe

    const float4* arow = reinterpret_cast<const float4*>(ah + (size_t)node * HID);
    const float4* hrow = reinterpret_cast<const float4*>(h + (size_t)node * HID);
    float4*       wrow = reinterpret_cast<float4*>(h + (size_t)node * HID);

    float ar[64], hr[64];
#pragma unroll
    for (int kq = 0; kq < 16; ++kq) {
        float4 va = arow[kq];
        ar[4 * kq] = va.x; ar[4 * kq + 1] = va.y; ar[4 * kq + 2] = va.z; ar[4 * kq + 3] = va.w;
        float4 vh = hrow[kq];
        hr[4 * kq] = vh.x; hr[4 * kq + 1] = vh.y; hr[4 * kq + 2] = vh.z; hr[4 * kq + 3] = vh.w;
    }

    for (int jt = 0; jt < 64; jt += 4) {
        // original h[jt..jt+3] for the z-blend (global re-read, L1-hot;
        // avoids runtime indexing into hr[] — rule #20)
        float4 hold4 = hrow[jt >> 2];

        float acc[4][6];
#pragma unroll
        for (int q = 0; q < 4; ++q) {
            acc[q][0] = b_ih[jt + q];
            acc[q][1] = b_ih[64 + jt + q];
            acc[q][2] = b_ih[128 + jt + q];
            acc[q][3] = b_hh[jt + q];
            acc[q][4] = b_hh[64 + jt + q];
            acc[q][5] = b_hh[128 + jt + q];
        }

#pragma unroll
        for (int kq = 0; kq < 16; ++kq) {
            float a0 = ar[4 * kq], a1 = ar[4 * kq + 1], a2 = ar[4 * kq + 2], a3 = ar[4 * kq + 3];
            float h0 = hr[4 * kq], h1 = hr[4 * kq + 1], h2 = hr[4 * kq + 2], h3 = hr[4 * kq + 3];
#pragma unroll
            for (int q = 0; q < 4; ++q) {
                // LDS reads at uniform (jt,q,kq)-indexed addresses: jt is the
                // only runtime term -> one v_addr per jt, imm offsets cover
                // the rest -> broadcast ds_read_b128, conflict-free
                const float4 w0 = *reinterpret_cast<const float4*>(&wi[(size_t)(jt + q) * 64 + 4 * kq]);
                const float4 w1 = *reinterpret_cast<const float4*>(&wi[(size_t)(64 + jt + q) * 64 + 4 * kq]);
                const float4 w2 = *reinterpret_cast<const float4*>(&wi[(size_t)(128 + jt + q) * 64 + 4 * kq]);
                const float4 w3 = *reinterpret_cast<const float4*>(&wh[(size_t)(jt + q) * 64 + 4 * kq]);
                const float4 w4 = *reinterpret_cast<const float4*>(&wh[(size_t)(64 + jt + q) * 64 + 4 * kq]);
                const float4 w5 = *reinterpret_cast<const float4*>(&wh[(size_t)(128 + jt + q) * 64 + 4 * kq]);
                acc[q][0] = fmaf(a0, w0.x, acc[q][0]); acc[q][0] = fmaf(a1, w0.y, acc[q][0]);
                acc[q][0] = fmaf(a2, w0.z, acc[q][0]); acc[q][0] = fmaf(a3, w0.w, acc[q][0]);
                acc[q][1] = fmaf(a0, w1.x, acc[q][1]); acc[q][1] = fmaf(a1, w1.y, acc[q][1]);
                acc[q][1] = fmaf(a2, w1.z, acc[q][1]); acc[q][1] = fmaf(a3, w1.w, acc[q][1]);
                acc[q][2] = fmaf(a0, w2.x, acc[q][2]); acc[q][2] = fmaf(a1, w2.y, acc[q][2]);
                acc[q][2] = fmaf(a2, w2.z, acc[q][2]); acc[q][2] = fmaf(a3, w2.w, acc[q][2]);
                acc[q][3] = fmaf(h0, w3.x, acc[q][3]); acc[q][3] = fmaf(h1, w3.y, acc[q][3]);
                acc[q][3] = fmaf(h2, w3.z, acc[q][3]); acc[q][3] = fmaf(h3, w3.w, acc[q][3]);
                acc[q][4] = fmaf(h0, w4.x, acc[q][4]); acc[q][4] = fmaf(h1, w4.y, acc[q][4]);
                acc[q][4] = fmaf(h2, w4.z, acc[q][4]); acc[q][4] = fmaf(h3, w4.w, acc[q][4]);
                acc[q][5] = fmaf(h0, w5.x, acc[q][5]); acc[q][5] = fmaf(h1, w5.y, acc[q][5]);
                acc[q][5] = fmaf(h2, w5.z, acc[q][5]); acc[q][5] = fmaf(h3, w5.w, acc[q][5]);
            }
        }

        float val[4];
        const float hold[4] = {hold4.x, hold4.y, hold4.z, hold4.w};
#pragma unroll
        for (int q = 0; q < 4; ++q) {
            float r  = 1.f / (1.f + __expf(-(acc[q][0] + acc[q][3])));
            float z  = 1.f / (1.f + __expf(-(acc[q][1] + acc[q][4])));
            float x2 = acc[q][2] + r * acc[q][5];
            float nn = 1.f - 2.f / (__expf(2.f * x2) + 1.f);  // tanh, inf-safe
            val[q] = (1.f - z) * nn + z * hold[q];
        }
        wrow[jt >> 2] = make_float4(val[0], val[1], val[2], val[3]);
    }
}

// ---------------------------------------------------------------------------
// out = softmax(h @ w2.T + b2)  wave per node; lane<40 = class; w2 in VGPRs
// ---------------------------------------------------------------------------
__global__ __launch_bounds__(256) void k_out(
    const float* __restrict__ h, const float* __restrict__ w2,
    const float* __restrict__ b2, float* __restrict__ out, int n_nodes)
{
    const int tid = threadIdx.x, lane = tid & 63;
    float wreg[64];
    float bias = 0.f;
    if (lane < NCLASS) {
#pragma unroll
        for (int k = 0; k < 64; k += 4) {
            float4 v = *reinterpret_cast<const float4*>(&w2[lane * HID + k]);
            wreg[k] = v.x; wreg[k + 1] = v.y; wreg[k + 2] = v.z; wreg[k + 3] = v.w;
        }
        bias = b2[lane];
    } else {
#pragma unroll
        for (int k = 0; k < 64; ++k) wreg[k] = 0.f;
    }
    int wid    = (blockIdx.x * blockDim.x + tid) >> 6;
    int nwaves = (gridDim.x * blockDim.x) >> 6;
    for (int node = wid; node < n_nodes; node += nwaves) {
        const float4* r4 = reinterpret_cast<const float4*>(h + (size_t)node * HID);
        float a0 = bias, a1 = 0.f, a2 = 0.f, a3 = 0.f;
#pragma unroll
        for (int kq = 0; kq < 16; ++kq) {
            float4 v = r4[kq];
            a0 = fmaf(v.x, wreg[4 * kq + 0], a0);
            a1 = fmaf(v.y, wreg[4 * kq + 1], a1);
            a2 = fmaf(v.z, wreg[4 * kq + 2], a2);
            a3 = fmaf(v.w, wreg[4 * kq + 3], a3);
        }
        float lg = (lane < NCLASS) ? (a0 + a1) + (a2 + a3) : -INFINITY;
        float m = lg;
#pragma unroll
        for (int off = 32; off > 0; off >>= 1) m = fmaxf(m, __shfl_xor(m, off, 64));
        float p = (lane < NCLASS) ? __expf(lg - m) : 0.f;
        float s = p;
#pragma unroll
        for (int off = 32; off > 0; off >>= 1) s += __shfl_xor(s, off, 64);
        if (lane < NCLASS) out[(size_t)node * NCLASS + lane] = p / s;
    }
}

// ---------------------------------------------------------------------------
extern "C" void kernel_launch(void* const* d_in, const int* in_sizes, int n_in,
                              void* d_out, int out_size, void* d_ws, size_t ws_size,
                              hipStream_t stream)
{
    const float* x    = (const float*)d_in[0];
    const int*   ei   = (const int*)d_in[1];    // int32 per harness contract
    const float* w1   = (const float*)d_in[2];
    const float* b1   = (const float*)d_in[3];
    const float* gg_w = (const float*)d_in[4];
    const float* w_ih = (const float*)d_in[5];
    const float* w_hh = (const float*)d_in[6];
    const float* b_ih = (const float*)d_in[7];
    const float* b_hh = (const float*)d_in[8];
    const float* w2   = (const float*)d_in[9];
    const float* b2   = (const float*)d_in[10];
    float*       out  = (float*)d_out;

    const int n = in_sizes[0] / NFEAT;   // 200000
    const int E = in_sizes[1] / 2;       // 1200000

    // workspace carve (~110 MB), 256-B aligned slots
    char* ws0 = (char*)d_ws;
    char* ws  = ws0;
    auto carve = [&](size_t bytes) {
        char* p = ws;
        ws += (bytes + 255) & ~(size_t)255;
        return p;
    };
    float* h       = (float*)carve((size_t)n * HID * 4);
    float* ah      = (float*)carve((size_t)n * HID * 4);
    float* Wic     = (float*)carve((size_t)NUM_LAYERS * 192 * 64 * 4);
    int*   row_ptr = (int*)carve((size_t)(n + 1) * 4);
    int*   col_src = (int*)carve((size_t)E * 4);
    int*   cnt     = (int*)carve((size_t)n * 4);
    int*   cursor  = (int*)carve((size_t)n * 4);
    int*   btot    = (int*)carve(8192);

    const int nb = (n + SCAN_C - 1) / SCAN_C;

    hipMemsetAsync(cnt, 0, (size_t)n * 4, stream);
    k_wic<<<(NUM_LAYERS * 192 * 64 + 255) / 256, 256, 0, stream>>>(gg_w, w_ih, Wic);
    k_lin1<<<2048, 256, 0, stream>>>(x, w1, b1, h, n);
    k_hist<<<(E + 255) / 256, 256, 0, stream>>>(ei, cnt, E);
    k_scan1<<<nb, 512, 0, stream>>>(cnt, btot, n);
    k_scan2<<<1, 1024, 0, stream>>>(btot, nb);
    k_scan3<<<nb, 512, 0, stream>>>(cnt, btot, row_ptr, cursor, n);
    k_fill<<<(E + 255) / 256, 256, 0, stream>>>(ei, cursor, col_src, E);

    const int ngrp = (n + G7_BLK - 1) / G7_BLK;  // 782
    for (int l = 0; l < NUM_LAYERS; ++l) {
        k_agg<<<2048, 256, 0, stream>>>(h, row_ptr, col_src, ah, n);
        k_gru7<<<ngrp, G7_BLK, 0, stream>>>(ah, h, Wic + (size_t)l * 192 * 64,
                                            w_hh, b_ih, b_hh, n);
    }
    k_out<<<2048, 256, 0, stream>>>(h, w2, b2, out, n);
}

// Round 16
// 1146.705 us; speedup vs baseline: 2.6971x; 2.6971x over previous
//
#include <hip/hip_runtime.h>
#include <hip/hip_bf16.h>

#define NFEAT 256
#define HID 64
#define NCLASS 40
#define NUM_LAYERS 3

typedef unsigned short u16;
typedef float f32x4 __attribute__((ext_vector_type(4)));
typedef short s16x8 __attribute__((ext_vector_type(8)));

// fp16 hi/lo split: hi = (f16)f, lo = (f16)(f - hi) -> ~22-23 mantissa bits
__device__ __forceinline__ u16 f2h(float f) {
    _Float16 h = (_Float16)f;
    return __builtin_bit_cast(u16, h);
}
__device__ __forceinline__ float h2f(u16 s) {
    return (float)__builtin_bit_cast(_Float16, s);
}

// inline-asm MFMA (f16 variant, same 4+4+4 VGPR layout as bf16 — ISA §10)
__device__ __forceinline__ f32x4 mfma_f16(s16x8 a, s16x8 b, f32x4 c) {
    asm("v_mfma_f32_16x16x32_f16 %0, %1, %2, %0" : "+v"(c) : "v"(a), "v"(b));
    return c;
}

// ---------------------------------------------------------------------------
// lin1: h = relu(x @ w1.T + b1) -> written as f16 hi/lo into X[:,64:128]
// ---------------------------------------------------------------------------
__global__ __launch_bounds__(256) void k_lin1(
    const float* __restrict__ x, const float* __restrict__ w1,
    const float* __restrict__ b1, u16* Xhi, u16* Xlo, int n_nodes)
{
    __shared__ float xs[8][NFEAT];
    __shared__ float part[4][8][HID];
    const int tid  = threadIdx.x;
    const int wave = tid >> 6;
    const int lane = tid & 63;

    float wreg[64];
#pragma unroll
    for (int k = 0; k < 64; k += 4) {
        float4 v = *reinterpret_cast<const float4*>(&w1[lane * NFEAT + wave * 64 + k]);
        wreg[k] = v.x; wreg[k + 1] = v.y; wreg[k + 2] = v.z; wreg[k + 3] = v.w;
    }

    const int nbatch = (n_nodes + 7) >> 3;
    for (int batch = blockIdx.x; batch < nbatch; batch += gridDim.x) {
        const int n0 = batch * 8;
        {
            const float4* xg = reinterpret_cast<const float4*>(x + (size_t)n0 * NFEAT);
            float4* xsv = reinterpret_cast<float4*>(&xs[0][0]);
#pragma unroll
            for (int i = 0; i < 2; ++i) {
                int idx  = tid + i * 256;
                int node = n0 + (idx >> 6);
                xsv[idx] = (node < n_nodes) ? xg[idx] : make_float4(0.f, 0.f, 0.f, 0.f);
            }
        }
        __syncthreads();
        for (int nl = 0; nl < 8; ++nl) {
            const float4* xrow = reinterpret_cast<const float4*>(&xs[nl][wave * 64]);
            float a0 = 0.f, a1 = 0.f, a2 = 0.f, a3 = 0.f;
#pragma unroll
            for (int kq = 0; kq < 16; ++kq) {
                float4 v = xrow[kq];
                a0 = fmaf(v.x, wreg[4 * kq + 0], a0);
                a1 = fmaf(v.y, wreg[4 * kq + 1], a1);
                a2 = fmaf(v.z, wreg[4 * kq + 2], a2);
                a3 = fmaf(v.w, wreg[4 * kq + 3], a3);
            }
            part[wave][nl][lane] = (a0 + a1) + (a2 + a3);
        }
        __syncthreads();
#pragma unroll
        for (int i = 0; i < 2; ++i) {
            int o = tid + i * 256;
            int nl = o >> 6, j = o & 63;
            int node = n0 + nl;
            if (node < n_nodes) {
                float v = part[0][nl][j] + part[1][nl][j] + part[2][nl][j] + part[3][nl][j]
                          + b1[j];
                float hv = fmaxf(v, 0.f);
                u16 hi = f2h(hv);
                Xhi[(size_t)node * 128 + 64 + j] = hi;
                Xlo[(size_t)node * 128 + 64 + j] = f2h(hv - h2f(hi));
            }
        }
        __syncthreads();
    }
}

// ---------------------------------------------------------------------------
// CSR build (int32 edge_index)
// ---------------------------------------------------------------------------
__global__ void k_hist(const int* __restrict__ ei, int* __restrict__ cnt, int E)
{
    int i = blockIdx.x * blockDim.x + threadIdx.x;
    if (i < E) atomicAdd(&cnt[ei[E + i]], 1);
}

#define SCAN_C 2048
__global__ __launch_bounds__(512) void k_scan1(const int* __restrict__ cnt,
                                               int* __restrict__ btot, int n)
{
    __shared__ int sd[512];
    int b = blockIdx.x, t = threadIdx.x;
    int base = b * SCAN_C + t * 4;
    int s = 0;
#pragma unroll
    for (int i = 0; i < 4; ++i) { int idx = base + i; if (idx < n) s += cnt[idx]; }
    sd[t] = s; __syncthreads();
    for (int off = 256; off > 0; off >>= 1) {
        if (t < off) sd[t] += sd[t + off];
        __syncthreads();
    }
    if (t == 0) btot[b] = sd[0];
}

__global__ __launch_bounds__(1024) void k_scan2(int* __restrict__ btot, int nb)
{
    __shared__ int sd[1024];
    int t = threadIdx.x;
    int v = (t < nb) ? btot[t] : 0;
    sd[t] = v; __syncthreads();
    for (int off = 1; off < 1024; off <<= 1) {
        int x = sd[t];
        int add = (t >= off) ? sd[t - off] : 0;
        __syncthreads();
        sd[t] = x + add;
        __syncthreads();
    }
    if (t < nb) btot[t] = sd[t] - v;  // exclusive
}

__global__ __launch_bounds__(512) void k_scan3(const int* __restrict__ cnt,
                                               const int* __restrict__ btot,
                                               int* __restrict__ row_ptr,
                                               int* __restrict__ cursor, int n)
{
    __shared__ int sth[512];
    int b = blockIdx.x, t = threadIdx.x;
    int base = b * SCAN_C + t * 4;
    int v[4]; int s = 0;
#pragma unroll
    for (int i = 0; i < 4; ++i) { int idx = base + i; v[i] = (idx < n) ? cnt[idx] : 0; s += v[i]; }
    sth[t] = s; __syncthreads();
    int mine = s;
    for (int off = 1; off < 512; off <<= 1) {
        int x = sth[t];
        int add = (t >= off) ? sth[t - off] : 0;
        __syncthreads();
        sth[t] = x + add;
        __syncthreads();
    }
    int carry = btot[b] + (sth[t] - mine);
#pragma unroll
    for (int i = 0; i < 4; ++i) {
        int idx = base + i;
        if (idx < n) {
            row_ptr[idx] = carry;
            cursor[idx]  = carry;
            carry += v[i];
            if (idx == n - 1) row_ptr[n] = carry;  // = E
        }
    }
}

__global__ void k_fill(const int* __restrict__ ei, int* __restrict__ cursor,
                       int* __restrict__ col_src, int E)
{
    int i = blockIdx.x * blockDim.x + threadIdx.x;
    if (i < E) {
        int dst = ei[E + i];
        int p = atomicAdd(&cursor[dst], 1);
        col_src[p] = ei[i];
    }
}

// ---------------------------------------------------------------------------
// aggregation v2: gathers h from X h-halves (f16 hi+lo), writes ah as f16
// hi/lo into X[:,0:64]. Wave per node, lane = feat. fp32 accumulation.
// ---------------------------------------------------------------------------
__global__ __launch_bounds__(256) void k_agg2(
    u16* Xhi, u16* Xlo, const int* __restrict__ row_ptr,
    const int* __restrict__ col_src, int n_nodes)
{
    int wid    = (blockIdx.x * blockDim.x + threadIdx.x) >> 6;
    int lane   = threadIdx.x & 63;
    int nwaves = (gridDim.x * blockDim.x) >> 6;
    for (int node = wid; node < n_nodes; node += nwaves) {
        int e0 = row_ptr[node], e1 = row_ptr[node + 1];
        float acc = 0.f;
        int e = e0;
        for (; e + 4 <= e1; e += 4) {
            int s0 = col_src[e], s1 = col_src[e + 1], s2 = col_src[e + 2], s3 = col_src[e + 3];
            float v0 = h2f(Xhi[(size_t)s0 * 128 + 64 + lane]) + h2f(Xlo[(size_t)s0 * 128 + 64 + lane]);
            float v1 = h2f(Xhi[(size_t)s1 * 128 + 64 + lane]) + h2f(Xlo[(size_t)s1 * 128 + 64 + lane]);
            float v2 = h2f(Xhi[(size_t)s2 * 128 + 64 + lane]) + h2f(Xlo[(size_t)s2 * 128 + 64 + lane]);
            float v3 = h2f(Xhi[(size_t)s3 * 128 + 64 + lane]) + h2f(Xlo[(size_t)s3 * 128 + 64 + lane]);
            acc += (v0 + v1) + (v2 + v3);
        }
        for (; e < e1; ++e) {
            int s = col_src[e];
            acc += h2f(Xhi[(size_t)s * 128 + 64 + lane]) + h2f(Xlo[(size_t)s * 128 + 64 + lane]);
        }
        u16 hi = f2h(acc);
        Xhi[(size_t)node * 128 + lane] = hi;
        Xlo[(size_t)node * 128 + lane] = f2h(acc - h2f(hi));
    }
}

// ---------------------------------------------------------------------------
// Wic[l][j][k] = sum_m w_ih[j][m] * gg_w[l][k][m]  (fp32 staging)
// ---------------------------------------------------------------------------
__global__ void k_wic(const float* __restrict__ gg_w, const float* __restrict__ w_ih,
                      float* __restrict__ Wic)
{
    int idx = blockIdx.x * blockDim.x + threadIdx.x;
    if (idx < NUM_LAYERS * 192 * 64) {
        int l = idx / (192 * 64);
        int j = (idx / 64) % 192;
        int k = idx % 64;
        const float* gw = gg_w + ((size_t)l * 64 + k) * 64;
        const float* wi = w_ih + (size_t)j * 64;
        float acc = 0.f;
#pragma unroll 4
        for (int m = 0; m < 64; ++m) acc = fmaf(wi[m], gw[m], acc);
        Wic[idx] = acc;
    }
}

// ---------------------------------------------------------------------------
// W' pack: [3][256][128] f16 hi/lo. Rows 0-127: [Wic_rz | whh_rz] (r,z sums
// fold into one GEMM); 128-191: [Wic_n | 0] (i_n); 192-255: [0 | whh_n] (h_n).
// ---------------------------------------------------------------------------
__global__ void k_wpack(const float* __restrict__ Wic, const float* __restrict__ whh,
                        u16* __restrict__ Wphi, u16* __restrict__ Wplo)
{
    int idx = blockIdx.x * 256 + threadIdx.x;
    if (idx >= NUM_LAYERS * 256 * 128) return;
    int l = idx / (256 * 128);
    int n = (idx / 128) & 255;
    int k = idx & 127;
    float v;
    if (n < 128)      v = (k < 64) ? Wic[((size_t)l * 192 + n) * 64 + k] : whh[(size_t)n * 64 + (k - 64)];
    else if (n < 192) v = (k < 64) ? Wic[((size_t)l * 192 + n) * 64 + k] : 0.f;
    else              v = (k < 64) ? 0.f : whh[(size_t)(n - 64) * 64 + (k - 64)];
    u16 hi = f2h(v);
    Wphi[idx] = hi;
    Wplo[idx] = f2h(v - h2f(hi));
}

// ---------------------------------------------------------------------------
// fused GRU v8b — MFMA, fp16 hi/lo, FULL 4-term product (exact in fp32 acc:
// 11+11 mantissa bits < 24). r15's bf16 3-term failed at absmax 1.22e-3 vs
// 1.12e-3 threshold; fp16 4-term cuts rep error 2^-16 -> 2^-22.
// C[64 nodes, 256 gates] = X[.,128] @ W'^T via 16x16x32_f16.
// Wave = 16 nodes; block = 4 waves. Valid k-steps: tiles 0-7 (r,z): s 0-3;
// 8-11 (i_n): s 0-1; 12-15 (h_n): s 2-3 -> 48 pairs x 4 MFMA = 192/wave.
// ~100 VGPR, zero LDS, zero barriers (r3-r14 lessons: spill-proof by design).
// ---------------------------------------------------------------------------
__global__ __launch_bounds__(256) void k_gru8(
    u16* Xhi, u16* Xlo,
    const u16* __restrict__ Wphi, const u16* __restrict__ Wplo,
    const float* __restrict__ b_ih, const float* __restrict__ b_hh, int n_nodes)
{
    const int l    = threadIdx.x & 63;
    const int wv   = threadIdx.x >> 6;
    const int base = blockIdx.x * 64 + wv * 16;
    if (base >= n_nodes) return;

    const int lrow = l & 15;
    const int lk   = (l >> 4) * 8;

    int arow = base + lrow;
    if (arow > n_nodes - 1) arow = n_nodes - 1;
    const u16* xh = Xhi + (size_t)arow * 128;
    const u16* xl = Xlo + (size_t)arow * 128;

    f32x4 acc[16];
#pragma unroll
    for (int t = 0; t < 16; ++t) acc[t] = f32x4{0.f, 0.f, 0.f, 0.f};

#pragma unroll
    for (int s = 0; s < 4; ++s) {
        s16x8 ahi = *reinterpret_cast<const s16x8*>(xh + s * 32 + lk);
        s16x8 alo = *reinterpret_cast<const s16x8*>(xl + s * 32 + lk);
#pragma unroll
        for (int t = 0; t < 16; ++t) {
            const bool valid = (t < 8) || (t < 12 ? (s < 2) : (s >= 2));
            if (!valid) continue;  // compile-time after unroll
            const size_t woff = (size_t)(t * 16 + lrow) * 128 + s * 32 + lk;
            s16x8 bhi = *reinterpret_cast<const s16x8*>(Wphi + woff);
            s16x8 blo = *reinterpret_cast<const s16x8*>(Wplo + woff);
            acc[t] = mfma_f16(ahi, bhi, acc[t]);
            acc[t] = mfma_f16(alo, bhi, acc[t]);
            acc[t] = mfma_f16(ahi, blo, acc[t]);
            acc[t] = mfma_f16(alo, blo, acc[t]);
        }
    }

    const int quarter = l >> 4;
    const int c = lrow;
#pragma unroll
    for (int r = 0; r < 4; ++r) {
        int m = base + quarter * 4 + r;
        if (m < n_nodes) {
            u16* hh = Xhi + (size_t)m * 128 + 64;
            u16* hl = Xlo + (size_t)m * 128 + 64;
#pragma unroll
            for (int q = 0; q < 4; ++q) {
                int j = q * 16 + c;
                float rv = acc[q][r]      + b_ih[j]       + b_hh[j];
                float zv = acc[4 + q][r]  + b_ih[64 + j]  + b_hh[64 + j];
                float iv = acc[8 + q][r]  + b_ih[128 + j];
                float hv = acc[12 + q][r] + b_hh[128 + j];
                rv = 1.f / (1.f + __expf(-rv));
                zv = 1.f / (1.f + __expf(-zv));
                float x2 = iv + rv * hv;
                float nn = 1.f - 2.f / (__expf(2.f * x2) + 1.f);  // tanh, inf-safe
                float hold = h2f(hh[j]) + h2f(hl[j]);
                float hnw  = (1.f - zv) * nn + zv * hold;
                u16 nhi = f2h(hnw);
                hh[j] = nhi;
                hl[j] = f2h(hnw - h2f(nhi));
            }
        }
    }
}

// ---------------------------------------------------------------------------
// out = softmax(h @ w2.T + b2); h read from X h-halves (hi+lo reconstruct)
// ---------------------------------------------------------------------------
__global__ __launch_bounds__(256) void k_out(
    const u16* __restrict__ Xhi, const u16* __restrict__ Xlo,
    const float* __restrict__ w2, const float* __restrict__ b2,
    float* __restrict__ out, int n_nodes)
{
    const int tid = threadIdx.x, lane = tid & 63;
    float wreg[64];
    float bias = 0.f;
    if (lane < NCLASS) {
#pragma unroll
        for (int k = 0; k < 64; k += 4) {
            float4 v = *reinterpret_cast<const float4*>(&w2[lane * HID + k]);
            wreg[k] = v.x; wreg[k + 1] = v.y; wreg[k + 2] = v.z; wreg[k + 3] = v.w;
        }
        bias = b2[lane];
    } else {
#pragma unroll
        for (int k = 0; k < 64; ++k) wreg[k] = 0.f;
    }
    int wid    = (blockIdx.x * blockDim.x + tid) >> 6;
    int nwaves = (gridDim.x * blockDim.x) >> 6;
    for (int node = wid; node < n_nodes; node += nwaves) {
        const uint2* ph = reinterpret_cast<const uint2*>(Xhi + (size_t)node * 128 + 64);
        const uint2* pl = reinterpret_cast<const uint2*>(Xlo + (size_t)node * 128 + 64);
        float a0 = bias, a1 = 0.f, a2 = 0.f, a3 = 0.f;
#pragma unroll
        for (int kq = 0; kq < 16; ++kq) {
            uint2 uh = ph[kq], ul = pl[kq];
            float v0 = h2f((u16)(uh.x & 0xFFFF)) + h2f((u16)(ul.x & 0xFFFF));
            float v1 = h2f((u16)(uh.x >> 16))    + h2f((u16)(ul.x >> 16));
            float v2 = h2f((u16)(uh.y & 0xFFFF)) + h2f((u16)(ul.y & 0xFFFF));
            float v3 = h2f((u16)(uh.y >> 16))    + h2f((u16)(ul.y >> 16));
            a0 = fmaf(v0, wreg[4 * kq + 0], a0);
            a1 = fmaf(v1, wreg[4 * kq + 1], a1);
            a2 = fmaf(v2, wreg[4 * kq + 2], a2);
            a3 = fmaf(v3, wreg[4 * kq + 3], a3);
        }
        float lg = (lane < NCLASS) ? (a0 + a1) + (a2 + a3) : -INFINITY;
        float m = lg;
#pragma unroll
        for (int off = 32; off > 0; off >>= 1) m = fmaxf(m, __shfl_xor(m, off, 64));
        float p = (lane < NCLASS) ? __expf(lg - m) : 0.f;
        float s = p;
#pragma unroll
        for (int off = 32; off > 0; off >>= 1) s += __shfl_xor(s, off, 64);
        if (lane < NCLASS) out[(size_t)node * NCLASS + lane] = p / s;
    }
}

// ---------------------------------------------------------------------------
extern "C" void kernel_launch(void* const* d_in, const int* in_sizes, int n_in,
                              void* d_out, int out_size, void* d_ws, size_t ws_size,
                              hipStream_t stream)
{
    const float* x    = (const float*)d_in[0];
    const int*   ei   = (const int*)d_in[1];    // int32 per harness contract
    const float* w1   = (const float*)d_in[2];
    const float* b1   = (const float*)d_in[3];
    const float* gg_w = (const float*)d_in[4];
    const float* w_ih = (const float*)d_in[5];
    const float* w_hh = (const float*)d_in[6];
    const float* b_ih = (const float*)d_in[7];
    const float* b_hh = (const float*)d_in[8];
    const float* w2   = (const float*)d_in[9];
    const float* b2   = (const float*)d_in[10];
    float*       out  = (float*)d_out;

    const int n = in_sizes[0] / NFEAT;   // 200000
    const int E = in_sizes[1] / 2;       // 1200000

    // workspace carve (~110 MB: proven-safe envelope), 256-B aligned slots
    char* ws0 = (char*)d_ws;
    char* ws  = ws0;
    auto carve = [&](size_t bytes) {
        char* p = ws;
        ws += (bytes + 255) & ~(size_t)255;
        return p;
    };
    u16*   Xhi     = (u16*)carve((size_t)n * 128 * 2);               // 51.2 MB
    u16*   Xlo     = (u16*)carve((size_t)n * 128 * 2);               // 51.2 MB
    float* Wic     = (float*)carve((size_t)NUM_LAYERS * 192 * 64 * 4);
    u16*   Wphi    = (u16*)carve((size_t)NUM_LAYERS * 256 * 128 * 2);
    u16*   Wplo    = (u16*)carve((size_t)NUM_LAYERS * 256 * 128 * 2);
    int*   row_ptr = (int*)carve((size_t)(n + 1) * 4);
    int*   col_src = (int*)carve((size_t)E * 4);
    int*   cnt     = (int*)carve((size_t)n * 4);
    int*   cursor  = (int*)carve((size_t)n * 4);
    int*   btot    = (int*)carve(8192);

    const int nb = (n + SCAN_C - 1) / SCAN_C;

    hipMemsetAsync(cnt, 0, (size_t)n * 4, stream);
    k_wic<<<(NUM_LAYERS * 192 * 64 + 255) / 256, 256, 0, stream>>>(gg_w, w_ih, Wic);
    k_wpack<<<(NUM_LAYERS * 256 * 128 + 255) / 256, 256, 0, stream>>>(Wic, w_hh, Wphi, Wplo);
    k_lin1<<<2048, 256, 0, stream>>>(x, w1, b1, Xhi, Xlo, n);
    k_hist<<<(E + 255) / 256, 256, 0, stream>>>(ei, cnt, E);
    k_scan1<<<nb, 512, 0, stream>>>(cnt, btot, n);
    k_scan2<<<1, 1024, 0, stream>>>(btot, nb);
    k_scan3<<<nb, 512, 0, stream>>>(cnt, btot, row_ptr, cursor, n);
    k_fill<<<(E + 255) / 256, 256, 0, stream>>>(ei, cursor, col_src, E);

    const int gblocks = (n + 63) / 64;  // 3125
    for (int l = 0; l < NUM_LAYERS; ++l) {
        k_agg2<<<2048, 256, 0, stream>>>(Xhi, Xlo, row_ptr, col_src, n);
        k_gru8<<<gblocks, 256, 0, stream>>>(Xhi, Xlo,
                                            Wphi + (size_t)l * 256 * 128,
                                            Wplo + (size_t)l * 256 * 128,
                                            b_ih, b_hh, n);
    }
    k_out<<<2048, 256, 0, stream>>>(Xhi, Xlo, w2, b2, out, n);
}

// Round 19
// 1127.971 us; speedup vs baseline: 2.7419x; 1.0166x over previous
//
#include <hip/hip_runtime.h>
#include <hip/hip_bf16.h>

#define NFEAT 256
#define HID 64
#define NCLASS 40
#define NUM_LAYERS 3

typedef unsigned short u16;
typedef unsigned int   u32;
typedef float    f32x4 __attribute__((ext_vector_type(4)));
typedef short    s16x8 __attribute__((ext_vector_type(8)));
typedef _Float16 h16x8 __attribute__((ext_vector_type(8)));

// fp16 hi/lo split: hi = (f16)f, lo = (f16)(f - hi) -> ~22-23 mantissa bits
__device__ __forceinline__ u16 f2h(float f) {
    _Float16 h = (_Float16)f;
    return __builtin_bit_cast(u16, h);
}
__device__ __forceinline__ float h2f(u16 s) {
    return (float)__builtin_bit_cast(_Float16, s);
}
__device__ __forceinline__ u32 packhl(float f) {
    u16 hi = f2h(f);
    u16 lo = f2h(f - h2f(hi));
    return (u32)hi | ((u32)lo << 16);
}
__device__ __forceinline__ float unpackhl(u32 v) {
    return h2f((u16)v) + h2f((u16)(v >> 16));
}

// BUILTIN MFMA (r18 lesson: raw inline-asm MFMA is opaque to the backend's
// hazard recognizer — no s_nop insertion for acc-read-after-mfma, so any
// schedule perturbation produces garbage. The builtin gets full hazard
// handling from the compiler.)
__device__ __forceinline__ f32x4 mfma_f16(s16x8 a, s16x8 b, f32x4 c) {
    return __builtin_amdgcn_mfma_f32_16x16x32_f16(
        __builtin_bit_cast(h16x8, a), __builtin_bit_cast(h16x8, b), c, 0, 0, 0);
}

// ---------------------------------------------------------------------------
// lin1: h = relu(x @ w1.T + b1) -> packed f16 hi|lo u32 into Xpk[:,64:128]
// ---------------------------------------------------------------------------
__global__ __launch_bounds__(256) void k_lin1(
    const float* __restrict__ x, const float* __restrict__ w1,
    const float* __restrict__ b1, u32* Xpk, int n_nodes)
{
    __shared__ float xs[8][NFEAT];
    __shared__ float part[4][8][HID];
    const int tid  = threadIdx.x;
    const int wave = tid >> 6;
    const int lane = tid & 63;

    float wreg[64];
#pragma unroll
    for (int k = 0; k < 64; k += 4) {
        float4 v = *reinterpret_cast<const float4*>(&w1[lane * NFEAT + wave * 64 + k]);
        wreg[k] = v.x; wreg[k + 1] = v.y; wreg[k + 2] = v.z; wreg[k + 3] = v.w;
    }

    const int nbatch = (n_nodes + 7) >> 3;
    for (int batch = blockIdx.x; batch < nbatch; batch += gridDim.x) {
        const int n0 = batch * 8;
        {
            const float4* xg = reinterpret_cast<const float4*>(x + (size_t)n0 * NFEAT);
            float4* xsv = reinterpret_cast<float4*>(&xs[0][0]);
#pragma unroll
            for (int i = 0; i < 2; ++i) {
                int idx  = tid + i * 256;
                int node = n0 + (idx >> 6);
                xsv[idx] = (node < n_nodes) ? xg[idx] : make_float4(0.f, 0.f, 0.f, 0.f);
            }
        }
        __syncthreads();
        for (int nl = 0; nl < 8; ++nl) {
            const float4* xrow = reinterpret_cast<const float4*>(&xs[nl][wave * 64]);
            float a0 = 0.f, a1 = 0.f, a2 = 0.f, a3 = 0.f;
#pragma unroll
            for (int kq = 0; kq < 16; ++kq) {
                float4 v = xrow[kq];
                a0 = fmaf(v.x, wreg[4 * kq + 0], a0);
                a1 = fmaf(v.y, wreg[4 * kq + 1], a1);
                a2 = fmaf(v.z, wreg[4 * kq + 2], a2);
                a3 = fmaf(v.w, wreg[4 * kq + 3], a3);
            }
            part[wave][nl][lane] = (a0 + a1) + (a2 + a3);
        }
        __syncthreads();
#pragma unroll
        for (int i = 0; i < 2; ++i) {
            int o = tid + i * 256;
            int nl = o >> 6, j = o & 63;
            int node = n0 + nl;
            if (node < n_nodes) {
                float v = part[0][nl][j] + part[1][nl][j] + part[2][nl][j] + part[3][nl][j]
                          + b1[j];
                Xpk[(size_t)node * 128 + 64 + j] = packhl(fmaxf(v, 0.f));
            }
        }
        __syncthreads();
    }
}

// ---------------------------------------------------------------------------
// CSR build (int32 edge_index)
// ---------------------------------------------------------------------------
__global__ void k_hist(const int* __restrict__ ei, int* __restrict__ cnt, int E)
{
    int i = blockIdx.x * blockDim.x + threadIdx.x;
    if (i < E) atomicAdd(&cnt[ei[E + i]], 1);
}

#define SCAN_C 2048
__global__ __launch_bounds__(512) void k_scan1(const int* __restrict__ cnt,
                                               int* __restrict__ btot, int n)
{
    __shared__ int sd[512];
    int b = blockIdx.x, t = threadIdx.x;
    int base = b * SCAN_C + t * 4;
    int s = 0;
#pragma unroll
    for (int i = 0; i < 4; ++i) { int idx = base + i; if (idx < n) s += cnt[idx]; }
    sd[t] = s; __syncthreads();
    for (int off = 256; off > 0; off >>= 1) {
        if (t < off) sd[t] += sd[t + off];
        __syncthreads();
    }
    if (t == 0) btot[b] = sd[0];
}

__global__ __launch_bounds__(1024) void k_scan2(int* __restrict__ btot, int nb)
{
    __shared__ int sd[1024];
    int t = threadIdx.x;
    int v = (t < nb) ? btot[t] : 0;
    sd[t] = v; __syncthreads();
    for (int off = 1; off < 1024; off <<= 1) {
        int x = sd[t];
        int add = (t >= off) ? sd[t - off] : 0;
        __syncthreads();
        sd[t] = x + add;
        __syncthreads();
    }
    if (t < nb) btot[t] = sd[t] - v;  // exclusive
}

__global__ __launch_bounds__(512) void k_scan3(const int* __restrict__ cnt,
                                               const int* __restrict__ btot,
                                               int* __restrict__ row_ptr,
                                               int* __restrict__ cursor, int n)
{
    __shared__ int sth[512];
    int b = blockIdx.x, t = threadIdx.x;
    int base = b * SCAN_C + t * 4;
    int v[4]; int s = 0;
#pragma unroll
    for (int i = 0; i < 4; ++i) { int idx = base + i; v[i] = (idx < n) ? cnt[idx] : 0; s += v[i]; }
    sth[t] = s; __syncthreads();
    int mine = s;
    for (int off = 1; off < 512; off <<= 1) {
        int x = sth[t];
        int add = (t >= off) ? sth[t - off] : 0;
        __syncthreads();
        sth[t] = x + add;
        __syncthreads();
    }
    int carry = btot[b] + (sth[t] - mine);
#pragma unroll
    for (int i = 0; i < 4; ++i) {
        int idx = base + i;
        if (idx < n) {
            row_ptr[idx] = carry;
            cursor[idx]  = carry;
            carry += v[i];
            if (idx == n - 1) row_ptr[n] = carry;  // = E
        }
    }
}

__global__ void k_fill(const int* __restrict__ ei, int* __restrict__ cursor,
                       int* __restrict__ col_src, int E)
{
    int i = blockIdx.x * blockDim.x + threadIdx.x;
    if (i < E) {
        int dst = ei[E + i];
        int p = atomicAdd(&cursor[dst], 1);
        col_src[p] = ei[i];
    }
}

// ---------------------------------------------------------------------------
// aggregation v3: gathers h (packed u32 = f16 hi|lo) — ONE 4-B load per lane
// per edge. Writes packed ah into Xpk[:,0:64]. fp32 accumulation.
// ---------------------------------------------------------------------------
__global__ __launch_bounds__(256) void k_agg2(
    u32* Xpk, const int* __restrict__ row_ptr,
    const int* __restrict__ col_src, int n_nodes)
{
    int wid    = (blockIdx.x * blockDim.x + threadIdx.x) >> 6;
    int lane   = threadIdx.x & 63;
    int nwaves = (gridDim.x * blockDim.x) >> 6;
    for (int node = wid; node < n_nodes; node += nwaves) {
        int e0 = row_ptr[node], e1 = row_ptr[node + 1];
        float acc = 0.f;
        int e = e0;
        for (; e + 4 <= e1; e += 4) {
            int s0 = col_src[e], s1 = col_src[e + 1], s2 = col_src[e + 2], s3 = col_src[e + 3];
            float v0 = unpackhl(Xpk[(size_t)s0 * 128 + 64 + lane]);
            float v1 = unpackhl(Xpk[(size_t)s1 * 128 + 64 + lane]);
            float v2 = unpackhl(Xpk[(size_t)s2 * 128 + 64 + lane]);
            float v3 = unpackhl(Xpk[(size_t)s3 * 128 + 64 + lane]);
            acc += (v0 + v1) + (v2 + v3);
        }
        for (; e < e1; ++e)
            acc += unpackhl(Xpk[(size_t)col_src[e] * 128 + 64 + lane]);
        Xpk[(size_t)node * 128 + lane] = packhl(acc);
    }
}

// ---------------------------------------------------------------------------
// Wic[l][j][k] = sum_m w_ih[j][m] * gg_w[l][k][m]  (fp32 staging)
// ---------------------------------------------------------------------------
__global__ void k_wic(const float* __restrict__ gg_w, const float* __restrict__ w_ih,
                      float* __restrict__ Wic)
{
    int idx = blockIdx.x * blockDim.x + threadIdx.x;
    if (idx < NUM_LAYERS * 192 * 64) {
        int l = idx / (192 * 64);
        int j = (idx / 64) % 192;
        int k = idx % 64;
        const float* gw = gg_w + ((size_t)l * 64 + k) * 64;
        const float* wi = w_ih + (size_t)j * 64;
        float acc = 0.f;
#pragma unroll 4
        for (int m = 0; m < 64; ++m) acc = fmaf(wi[m], gw[m], acc);
        Wic[idx] = acc;
    }
}

// ---------------------------------------------------------------------------
// W' pack: [3][256][128] f16 hi/lo, SPLIT arrays (B-frags load s16x8 direct).
// Rows 0-127: [Wic_rz | whh_rz]; 128-191: [Wic_n | 0]; 192-255: [0 | whh_n].
// ---------------------------------------------------------------------------
__global__ void k_wpack(const float* __restrict__ Wic, const float* __restrict__ whh,
                        u16* __restrict__ Wphi, u16* __restrict__ Wplo)
{
    int idx = blockIdx.x * 256 + threadIdx.x;
    if (idx >= NUM_LAYERS * 256 * 128) return;
    int l = idx / (256 * 128);
    int n = (idx / 128) & 255;
    int k = idx & 127;
    float v;
    if (n < 128)      v = (k < 64) ? Wic[((size_t)l * 192 + n) * 64 + k] : whh[(size_t)n * 64 + (k - 64)];
    else if (n < 192) v = (k < 64) ? Wic[((size_t)l * 192 + n) * 64 + k] : 0.f;
    else              v = (k < 64) ? 0.f : whh[(size_t)(n - 64) * 64 + (k - 64)];
    u16 hi = f2h(v);
    Wphi[idx] = hi;
    Wplo[idx] = f2h(v - h2f(hi));
}

// ---------------------------------------------------------------------------
// fused GRU v8p — r16-verified tile structure (fp16 hi/lo 4-term, 16 acc
// tiles), builtin MFMA (hazard-safe), packed-u32 X. A-frags: 2x uint4 load
// + shufflevector unpack. C[64 nodes, 256 gates]; valid k-steps: tiles 0-7
// (r,z): s 0-3; 8-11 (i_n): s 0-1; 12-15 (h_n): s 2-3.
// ---------------------------------------------------------------------------
__global__ __launch_bounds__(256) void k_gru8(
    u32* Xpk,
    const u16* __restrict__ Wphi, const u16* __restrict__ Wplo,
    const float* __restrict__ b_ih, const float* __restrict__ b_hh, int n_nodes)
{
    const int l    = threadIdx.x & 63;
    const int wv   = threadIdx.x >> 6;
    const int base = blockIdx.x * 64 + wv * 16;
    if (base >= n_nodes) return;

    const int lrow = l & 15;
    const int lk   = (l >> 4) * 8;

    int arow = base + lrow;
    if (arow > n_nodes - 1) arow = n_nodes - 1;
    const u32* xp = Xpk + (size_t)arow * 128;

    f32x4 acc[16];
#pragma unroll
    for (int t = 0; t < 16; ++t) acc[t] = f32x4{0.f, 0.f, 0.f, 0.f};

#pragma unroll
    for (int s = 0; s < 4; ++s) {
        const uint4* pa = reinterpret_cast<const uint4*>(xp + s * 32 + lk);
        uint4 w0 = pa[0], w1 = pa[1];
        s16x8 p0 = __builtin_bit_cast(s16x8, w0);  // hi0,lo0,hi1,lo1,...
        s16x8 p1 = __builtin_bit_cast(s16x8, w1);
        s16x8 ahi = __builtin_shufflevector(p0, p1, 0, 2, 4, 6, 8, 10, 12, 14);
        s16x8 alo = __builtin_shufflevector(p0, p1, 1, 3, 5, 7, 9, 11, 13, 15);
#pragma unroll
        for (int t = 0; t < 16; ++t) {
            const bool valid = (t < 8) || (t < 12 ? (s < 2) : (s >= 2));
            if (!valid) continue;  // compile-time after unroll
            const size_t woff = (size_t)(t * 16 + lrow) * 128 + s * 32 + lk;
            s16x8 bhi = *reinterpret_cast<const s16x8*>(Wphi + woff);
            s16x8 blo = *reinterpret_cast<const s16x8*>(Wplo + woff);
            acc[t] = mfma_f16(ahi, bhi, acc[t]);
            acc[t] = mfma_f16(alo, bhi, acc[t]);
            acc[t] = mfma_f16(ahi, blo, acc[t]);
            acc[t] = mfma_f16(alo, blo, acc[t]);
        }
    }

    const int quarter = l >> 4;
    const int c = lrow;
#pragma unroll
    for (int r = 0; r < 4; ++r) {
        int m = base + quarter * 4 + r;
        if (m < n_nodes) {
            u32* hp = Xpk + (size_t)m * 128 + 64;
#pragma unroll
            for (int q = 0; q < 4; ++q) {
                int j = q * 16 + c;
                float rv = acc[q][r]      + b_ih[j]       + b_hh[j];
                float zv = acc[4 + q][r]  + b_ih[64 + j]  + b_hh[64 + j];
                float iv = acc[8 + q][r]  + b_ih[128 + j];
                float hv = acc[12 + q][r] + b_hh[128 + j];
                rv = 1.f / (1.f + __expf(-rv));
                zv = 1.f / (1.f + __expf(-zv));
                float x2 = iv + rv * hv;
                float nn = 1.f - 2.f / (__expf(2.f * x2) + 1.f);  // tanh, inf-safe
                float hold = unpackhl(hp[j]);
                hp[j] = packhl((1.f - zv) * nn + zv * hold);
            }
        }
    }
}

// ---------------------------------------------------------------------------
// out = softmax(h @ w2.T + b2); h read from packed Xpk h-half
// ---------------------------------------------------------------------------
__global__ __launch_bounds__(256) void k_out(
    const u32* __restrict__ Xpk, const float* __restrict__ w2,
    const float* __restrict__ b2, float* __restrict__ out, int n_nodes)
{
    const int tid = threadIdx.x, lane = tid & 63;
    float wreg[64];
    float bias = 0.f;
    if (lane < NCLASS) {
#pragma unroll
        for (int k = 0; k < 64; k += 4) {
            float4 v = *reinterpret_cast<const float4*>(&w2[lane * HID + k]);
            wreg[k] = v.x; wreg[k + 1] = v.y; wreg[k + 2] = v.z; wreg[k + 3] = v.w;
        }
        bias = b2[lane];
    } else {
#pragma unroll
        for (int k = 0; k < 64; ++k) wreg[k] = 0.f;
    }
    int wid    = (blockIdx.x * blockDim.x + tid) >> 6;
    int nwaves = (gridDim.x * blockDim.x) >> 6;
    for (int node = wid; node < n_nodes; node += nwaves) {
        const uint4* p4 = reinterpret_cast<const uint4*>(Xpk + (size_t)node * 128 + 64);
        float a0 = bias, a1 = 0.f, a2 = 0.f, a3 = 0.f;
#pragma unroll
        for (int kq = 0; kq < 16; ++kq) {
            uint4 v = p4[kq];
            a0 = fmaf(unpackhl(v.x), wreg[4 * kq + 0], a0);
            a1 = fmaf(unpackhl(v.y), wreg[4 * kq + 1], a1);
            a2 = fmaf(unpackhl(v.z), wreg[4 * kq + 2], a2);
            a3 = fmaf(unpackhl(v.w), wreg[4 * kq + 3], a3);
        }
        float lg = (lane < NCLASS) ? (a0 + a1) + (a2 + a3) : -INFINITY;
        float m = lg;
#pragma unroll
        for (int off = 32; off > 0; off >>= 1) m = fmaxf(m, __shfl_xor(m, off, 64));
        float p = (lane < NCLASS) ? __expf(lg - m) : 0.f;
        float s = p;
#pragma unroll
        for (int off = 32; off > 0; off >>= 1) s += __shfl_xor(s, off, 64);
        if (lane < NCLASS) out[(size_t)node * NCLASS + lane] = p / s;
    }
}

// ---------------------------------------------------------------------------
extern "C" void kernel_launch(void* const* d_in, const int* in_sizes, int n_in,
                              void* d_out, int out_size, void* d_ws, size_t ws_size,
                              hipStream_t stream)
{
    const float* x    = (const float*)d_in[0];
    const int*   ei   = (const int*)d_in[1];    // int32 per harness contract
    const float* w1   = (const float*)d_in[2];
    const float* b1   = (const float*)d_in[3];
    const float* gg_w = (const float*)d_in[4];
    const float* w_ih = (const float*)d_in[5];
    const float* w_hh = (const float*)d_in[6];
    const float* b_ih = (const float*)d_in[7];
    const float* b_hh = (const float*)d_in[8];
    const float* w2   = (const float*)d_in[9];
    const float* b2   = (const float*)d_in[10];
    float*       out  = (float*)d_out;

    const int n = in_sizes[0] / NFEAT;   // 200000
    const int E = in_sizes[1] / 2;       // 1200000

    // workspace carve (~110 MB, proven envelope), 256-B aligned slots
    char* ws0 = (char*)d_ws;
    char* ws  = ws0;
    auto carve = [&](size_t bytes) {
        char* p = ws;
        ws += (bytes + 255) & ~(size_t)255;
        return p;
    };
    u32*   Xpk     = (u32*)carve((size_t)n * 128 * 4);               // 102.4 MB
    float* Wic     = (float*)carve((size_t)NUM_LAYERS * 192 * 64 * 4);
    u16*   Wphi    = (u16*)carve((size_t)NUM_LAYERS * 256 * 128 * 2);
    u16*   Wplo    = (u16*)carve((size_t)NUM_LAYERS * 256 * 128 * 2);
    int*   row_ptr = (int*)carve((size_t)(n + 1) * 4);
    int*   col_src = (int*)carve((size_t)E * 4);
    int*   cnt     = (int*)carve((size_t)n * 4);
    int*   cursor  = (int*)carve((size_t)n * 4);
    int*   btot    = (int*)carve(8192);

    const int nb = (n + SCAN_C - 1) / SCAN_C;

    hipMemsetAsync(cnt, 0, (size_t)n * 4, stream);
    k_wic<<<(NUM_LAYERS * 192 * 64 + 255) / 256, 256, 0, stream>>>(gg_w, w_ih, Wic);
    k_wpack<<<(NUM_LAYERS * 256 * 128 + 255) / 256, 256, 0, stream>>>(Wic, w_hh, Wphi, Wplo);
    k_lin1<<<2048, 256, 0, stream>>>(x, w1, b1, Xpk, n);
    k_hist<<<(E + 255) / 256, 256, 0, stream>>>(ei, cnt, E);
    k_scan1<<<nb, 512, 0, stream>>>(cnt, btot, n);
    k_scan2<<<1, 1024, 0, stream>>>(btot, nb);
    k_scan3<<<nb, 512, 0, stream>>>(cnt, btot, row_ptr, cursor, n);
    k_fill<<<(E + 255) / 256, 256, 0, stream>>>(ei, cursor, col_src, E);

    const int gblocks = (n + 63) / 64;  // 3125
    for (int l = 0; l < NUM_LAYERS; ++l) {
        k_agg2<<<2048, 256, 0, stream>>>(Xpk, row_ptr, col_src, n);
        k_gru8<<<gblocks, 256, 0, stream>>>(Xpk,
                                            Wphi + (size_t)l * 256 * 128,
                                            Wplo + (size_t)l * 256 * 128,
                                            b_ih, b_hh, n);
    }
    k_out<<<2048, 256, 0, stream>>>(Xpk, w2, b2, out, n);
}

// Round 20
// 1104.246 us; speedup vs baseline: 2.8008x; 1.0215x over previous
//
#include <hip/hip_runtime.h>
#include <hip/hip_bf16.h>

#define NFEAT 256
#define HID 64
#define NCLASS 40
#define NUM_LAYERS 3

typedef unsigned short u16;
typedef unsigned int   u32;
typedef float    f32x4 __attribute__((ext_vector_type(4)));
typedef short    s16x8 __attribute__((ext_vector_type(8)));
typedef _Float16 h16x8 __attribute__((ext_vector_type(8)));

// fp16 hi/lo split: hi = (f16)f, lo = (f16)(f - hi) -> ~22-23 mantissa bits
__device__ __forceinline__ u16 f2h(float f) {
    _Float16 h = (_Float16)f;
    return __builtin_bit_cast(u16, h);
}
__device__ __forceinline__ float h2f(u16 s) {
    return (float)__builtin_bit_cast(_Float16, s);
}
__device__ __forceinline__ u32 packhl(float f) {
    u16 hi = f2h(f);
    u16 lo = f2h(f - h2f(hi));
    return (u32)hi | ((u32)lo << 16);
}
__device__ __forceinline__ float unpackhl(u32 v) {
    return h2f((u16)v) + h2f((u16)(v >> 16));
}

// BUILTIN MFMA (r18/r19 lesson: raw inline-asm MFMA is opaque to the hazard
// recognizer — builtin gets compiler-inserted wait states; r19 verified).
__device__ __forceinline__ f32x4 mfma_f16(s16x8 a, s16x8 b, f32x4 c) {
    return __builtin_amdgcn_mfma_f32_16x16x32_f16(
        __builtin_bit_cast(h16x8, a), __builtin_bit_cast(h16x8, b), c, 0, 0, 0);
}

// ---------------------------------------------------------------------------
// lin1: h = relu(x @ w1.T + b1) -> packed f16 hi|lo u32 into Xpk[:,64:128]
// ---------------------------------------------------------------------------
__global__ __launch_bounds__(256) void k_lin1(
    const float* __restrict__ x, const float* __restrict__ w1,
    const float* __restrict__ b1, u32* Xpk, int n_nodes)
{
    __shared__ float xs[8][NFEAT];
    __shared__ float part[4][8][HID];
    const int tid  = threadIdx.x;
    const int wave = tid >> 6;
    const int lane = tid & 63;

    float wreg[64];
#pragma unroll
    for (int k = 0; k < 64; k += 4) {
        float4 v = *reinterpret_cast<const float4*>(&w1[lane * NFEAT + wave * 64 + k]);
        wreg[k] = v.x; wreg[k + 1] = v.y; wreg[k + 2] = v.z; wreg[k + 3] = v.w;
    }

    const int nbatch = (n_nodes + 7) >> 3;
    for (int batch = blockIdx.x; batch < nbatch; batch += gridDim.x) {
        const int n0 = batch * 8;
        {
            const float4* xg = reinterpret_cast<const float4*>(x + (size_t)n0 * NFEAT);
            float4* xsv = reinterpret_cast<float4*>(&xs[0][0]);
#pragma unroll
            for (int i = 0; i < 2; ++i) {
                int idx  = tid + i * 256;
                int node = n0 + (idx >> 6);
                xsv[idx] = (node < n_nodes) ? xg[idx] : make_float4(0.f, 0.f, 0.f, 0.f);
            }
        }
        __syncthreads();
        for (int nl = 0; nl < 8; ++nl) {
            const float4* xrow = reinterpret_cast<const float4*>(&xs[nl][wave * 64]);
            float a0 = 0.f, a1 = 0.f, a2 = 0.f, a3 = 0.f;
#pragma unroll
            for (int kq = 0; kq < 16; ++kq) {
                float4 v = xrow[kq];
                a0 = fmaf(v.x, wreg[4 * kq + 0], a0);
                a1 = fmaf(v.y, wreg[4 * kq + 1], a1);
                a2 = fmaf(v.z, wreg[4 * kq + 2], a2);
                a3 = fmaf(v.w, wreg[4 * kq + 3], a3);
            }
            part[wave][nl][lane] = (a0 + a1) + (a2 + a3);
        }
        __syncthreads();
#pragma unroll
        for (int i = 0; i < 2; ++i) {
            int o = tid + i * 256;
            int nl = o >> 6, j = o & 63;
            int node = n0 + nl;
            if (node < n_nodes) {
                float v = part[0][nl][j] + part[1][nl][j] + part[2][nl][j] + part[3][nl][j]
                          + b1[j];
                Xpk[(size_t)node * 128 + 64 + j] = packhl(fmaxf(v, 0.f));
            }
        }
        __syncthreads();
    }
}

// ---------------------------------------------------------------------------
// CSR build (int32 edge_index)
// ---------------------------------------------------------------------------
__global__ void k_hist(const int* __restrict__ ei, int* __restrict__ cnt, int E)
{
    int i = blockIdx.x * blockDim.x + threadIdx.x;
    if (i < E) atomicAdd(&cnt[ei[E + i]], 1);
}

#define SCAN_C 2048
__global__ __launch_bounds__(512) void k_scan1(const int* __restrict__ cnt,
                                               int* __restrict__ btot, int n)
{
    __shared__ int sd[512];
    int b = blockIdx.x, t = threadIdx.x;
    int base = b * SCAN_C + t * 4;
    int s = 0;
#pragma unroll
    for (int i = 0; i < 4; ++i) { int idx = base + i; if (idx < n) s += cnt[idx]; }
    sd[t] = s; __syncthreads();
    for (int off = 256; off > 0; off >>= 1) {
        if (t < off) sd[t] += sd[t + off];
        __syncthreads();
    }
    if (t == 0) btot[b] = sd[0];
}

__global__ __launch_bounds__(1024) void k_scan2(int* __restrict__ btot, int nb)
{
    __shared__ int sd[1024];
    int t = threadIdx.x;
    int v = (t < nb) ? btot[t] : 0;
    sd[t] = v; __syncthreads();
    for (int off = 1; off < 1024; off <<= 1) {
        int x = sd[t];
        int add = (t >= off) ? sd[t - off] : 0;
        __syncthreads();
        sd[t] = x + add;
        __syncthreads();
    }
    if (t < nb) btot[t] = sd[t] - v;  // exclusive
}

__global__ __launch_bounds__(512) void k_scan3(const int* __restrict__ cnt,
                                               const int* __restrict__ btot,
                                               int* __restrict__ row_ptr,
                                               int* __restrict__ cursor, int n)
{
    __shared__ int sth[512];
    int b = blockIdx.x, t = threadIdx.x;
    int base = b * SCAN_C + t * 4;
    int v[4]; int s = 0;
#pragma unroll
    for (int i = 0; i < 4; ++i) { int idx = base + i; v[i] = (idx < n) ? cnt[idx] : 0; s += v[i]; }
    sth[t] = s; __syncthreads();
    int mine = s;
    for (int off = 1; off < 512; off <<= 1) {
        int x = sth[t];
        int add = (t >= off) ? sth[t - off] : 0;
        __syncthreads();
        sth[t] = x + add;
        __syncthreads();
    }
    int carry = btot[b] + (sth[t] - mine);
#pragma unroll
    for (int i = 0; i < 4; ++i) {
        int idx = base + i;
        if (idx < n) {
            row_ptr[idx] = carry;
            cursor[idx]  = carry;
            carry += v[i];
            if (idx == n - 1) row_ptr[n] = carry;  // = E
        }
    }
}

__global__ void k_fill(const int* __restrict__ ei, int* __restrict__ cursor,
                       int* __restrict__ col_src, int E)
{
    int i = blockIdx.x * blockDim.x + threadIdx.x;
    if (i < E) {
        int dst = ei[E + i];
        int p = atomicAdd(&cursor[dst], 1);
        col_src[p] = ei[i];
    }
}

// ---------------------------------------------------------------------------
// aggregation v3: gathers h (packed u32 = f16 hi|lo) — one 4-B load per lane
// per edge. Writes packed ah into Xpk[:,0:64]. fp32 accumulation.
// ---------------------------------------------------------------------------
__global__ __launch_bounds__(256) void k_agg2(
    u32* Xpk, const int* __restrict__ row_ptr,
    const int* __restrict__ col_src, int n_nodes)
{
    int wid    = (blockIdx.x * blockDim.x + threadIdx.x) >> 6;
    int lane   = threadIdx.x & 63;
    int nwaves = (gridDim.x * blockDim.x) >> 6;
    for (int node = wid; node < n_nodes; node += nwaves) {
        int e0 = row_ptr[node], e1 = row_ptr[node + 1];
        float acc = 0.f;
        int e = e0;
        for (; e + 4 <= e1; e += 4) {
            int s0 = col_src[e], s1 = col_src[e + 1], s2 = col_src[e + 2], s3 = col_src[e + 3];
            float v0 = unpackhl(Xpk[(size_t)s0 * 128 + 64 + lane]);
            float v1 = unpackhl(Xpk[(size_t)s1 * 128 + 64 + lane]);
            float v2 = unpackhl(Xpk[(size_t)s2 * 128 + 64 + lane]);
            float v3 = unpackhl(Xpk[(size_t)s3 * 128 + 64 + lane]);
            acc += (v0 + v1) + (v2 + v3);
        }
        for (; e < e1; ++e)
            acc += unpackhl(Xpk[(size_t)col_src[e] * 128 + 64 + lane]);
        Xpk[(size_t)node * 128 + lane] = packhl(acc);
    }
}

// ---------------------------------------------------------------------------
// Wic[l][j][k] = sum_m w_ih[j][m] * gg_w[l][k][m]  (fp32 staging)
// ---------------------------------------------------------------------------
__global__ void k_wic(const float* __restrict__ gg_w, const float* __restrict__ w_ih,
                      float* __restrict__ Wic)
{
    int idx = blockIdx.x * blockDim.x + threadIdx.x;
    if (idx < NUM_LAYERS * 192 * 64) {
        int l = idx / (192 * 64);
        int j = (idx / 64) % 192;
        int k = idx % 64;
        const float* gw = gg_w + ((size_t)l * 64 + k) * 64;
        const float* wi = w_ih + (size_t)j * 64;
        float acc = 0.f;
#pragma unroll 4
        for (int m = 0; m < 64; ++m) acc = fmaf(wi[m], gw[m], acc);
        Wic[idx] = acc;
    }
}

// ---------------------------------------------------------------------------
// W' pack: [3][256][128] f16 hi/lo, SPLIT arrays (B-frags load s16x8 direct).
// Rows 0-63: r; 64-127: z (both [Wic | whh]); 128-191: [Wic_n | 0];
// 192-255: [0 | whh_n].
// ---------------------------------------------------------------------------
__global__ void k_wpack(const float* __restrict__ Wic, const float* __restrict__ whh,
                        u16* __restrict__ Wphi, u16* __restrict__ Wplo)
{
    int idx = blockIdx.x * 256 + threadIdx.x;
    if (idx >= NUM_LAYERS * 256 * 128) return;
    int l = idx / (256 * 128);
    int n = (idx / 128) & 255;
    int k = idx & 127;
    float v;
    if (n < 128)      v = (k < 64) ? Wic[((size_t)l * 192 + n) * 64 + k] : whh[(size_t)n * 64 + (k - 64)];
    else if (n < 192) v = (k < 64) ? Wic[((size_t)l * 192 + n) * 64 + k] : 0.f;
    else              v = (k < 64) ? 0.f : whh[(size_t)(n - 64) * 64 + (k - 64)];
    u16 hi = f2h(v);
    Wphi[idx] = hi;
    Wplo[idx] = f2h(v - h2f(hi));
}

// ---------------------------------------------------------------------------
// fused GRU v9 — B-fragment reuse (r17 retry, now on hazard-safe builtin
// MFMA, which r19 verified). Wave = 32 nodes (2 groups of 16); 4 q-passes
// over gate-column groups j in [16q,16q+16). Per pass live acc = 2 groups x
// 4 slots {r,z,i_n,h_n} = 32 VGPR; each B hi/lo pair feeds 8 MFMAs (2 groups
// x 4 hi/lo terms) — B-loads/node HALVED vs r19 (which ran at MfmaUtil 8.9%,
// VALU 17%, HBM 7%: pure latency/issue-bound).
// Valid k-steps: r,z: s 0-3; i_n: s 0-1 (k<64); h_n: s 2-3 (k>=64).
// In-place h hazard: passes re-read X h-columns as A-frags, so new h values
// are DEFERRED in pend[2][4][4] (static indices, rule #20) and written after
// all passes. Clamped tail rows only ever corrupt outputs with m>=n_nodes,
// which are never written (same argument as r16/r19).
// Peak VGPR ~110 < 128 heuristic cap — spill-proof (r3-r14 lessons).
// ---------------------------------------------------------------------------
__global__ __launch_bounds__(256) void k_gru9(
    u32* Xpk,
    const u16* __restrict__ Wphi, const u16* __restrict__ Wplo,
    const float* __restrict__ b_ih, const float* __restrict__ b_hh, int n_nodes)
{
    const int l    = threadIdx.x & 63;
    const int wv   = threadIdx.x >> 6;
    const int base = blockIdx.x * 128 + wv * 32;
    if (base >= n_nodes) return;

    const int lrow    = l & 15;
    const int lk      = (l >> 4) * 8;
    const int quarter = l >> 4;
    const int c       = lrow;

    const u32* xp0; const u32* xp1;
    {
        int a0 = base + lrow;       if (a0 > n_nodes - 1) a0 = n_nodes - 1;
        int a1 = base + 16 + lrow;  if (a1 > n_nodes - 1) a1 = n_nodes - 1;
        xp0 = Xpk + (size_t)a0 * 128;
        xp1 = Xpk + (size_t)a1 * 128;
    }

    float pend[2][4][4];

#pragma unroll
    for (int q = 0; q < 4; ++q) {
        f32x4 acc[2][4];
#pragma unroll
        for (int g = 0; g < 2; ++g)
#pragma unroll
            for (int t = 0; t < 4; ++t) acc[g][t] = f32x4{0.f, 0.f, 0.f, 0.f};

#pragma unroll
        for (int s = 0; s < 4; ++s) {
            // A-frags, both groups (packed u32 -> hi/lo via shufflevector)
            s16x8 ahi0, alo0, ahi1, alo1;
            {
                const uint4* pa = reinterpret_cast<const uint4*>(xp0 + s * 32 + lk);
                uint4 w0 = pa[0], w1 = pa[1];
                s16x8 p0 = __builtin_bit_cast(s16x8, w0);
                s16x8 p1 = __builtin_bit_cast(s16x8, w1);
                ahi0 = __builtin_shufflevector(p0, p1, 0, 2, 4, 6, 8, 10, 12, 14);
                alo0 = __builtin_shufflevector(p0, p1, 1, 3, 5, 7, 9, 11, 13, 15);
            }
            {
                const uint4* pa = reinterpret_cast<const uint4*>(xp1 + s * 32 + lk);
                uint4 w0 = pa[0], w1 = pa[1];
                s16x8 p0 = __builtin_bit_cast(s16x8, w0);
                s16x8 p1 = __builtin_bit_cast(s16x8, w1);
                ahi1 = __builtin_shufflevector(p0, p1, 0, 2, 4, 6, 8, 10, 12, 14);
                alo1 = __builtin_shufflevector(p0, p1, 1, 3, 5, 7, 9, 11, 13, 15);
            }

            // r-gate tile (t = q)
            {
                const size_t woff = (size_t)((q) * 16 + lrow) * 128 + s * 32 + lk;
                s16x8 bhi = *reinterpret_cast<const s16x8*>(Wphi + woff);
                s16x8 blo = *reinterpret_cast<const s16x8*>(Wplo + woff);
                acc[0][0] = mfma_f16(ahi0, bhi, acc[0][0]);
                acc[0][0] = mfma_f16(alo0, bhi, acc[0][0]);
                acc[0][0] = mfma_f16(ahi0, blo, acc[0][0]);
                acc[0][0] = mfma_f16(alo0, blo, acc[0][0]);
                acc[1][0] = mfma_f16(ahi1, bhi, acc[1][0]);
                acc[1][0] = mfma_f16(alo1, bhi, acc[1][0]);
                acc[1][0] = mfma_f16(ahi1, blo, acc[1][0]);
                acc[1][0] = mfma_f16(alo1, blo, acc[1][0]);
            }
            // z-gate tile (t = 4+q)
            {
                const size_t woff = (size_t)((4 + q) * 16 + lrow) * 128 + s * 32 + lk;
                s16x8 bhi = *reinterpret_cast<const s16x8*>(Wphi + woff);
                s16x8 blo = *reinterpret_cast<const s16x8*>(Wplo + woff);
                acc[0][1] = mfma_f16(ahi0, bhi, acc[0][1]);
                acc[0][1] = mfma_f16(alo0, bhi, acc[0][1]);
                acc[0][1] = mfma_f16(ahi0, blo, acc[0][1]);
                acc[0][1] = mfma_f16(alo0, blo, acc[0][1]);
                acc[1][1] = mfma_f16(ahi1, bhi, acc[1][1]);
                acc[1][1] = mfma_f16(alo1, bhi, acc[1][1]);
                acc[1][1] = mfma_f16(ahi1, blo, acc[1][1]);
                acc[1][1] = mfma_f16(alo1, blo, acc[1][1]);
            }
            // i_n (s<2, slot 2) or h_n (s>=2, slot 3); s compile-time
            if (s < 2) {
                const size_t woff = (size_t)((8 + q) * 16 + lrow) * 128 + s * 32 + lk;
                s16x8 bhi = *reinterpret_cast<const s16x8*>(Wphi + woff);
                s16x8 blo = *reinterpret_cast<const s16x8*>(Wplo + woff);
                acc[0][2] = mfma_f16(ahi0, bhi, acc[0][2]);
                acc[0][2] = mfma_f16(alo0, bhi, acc[0][2]);
                acc[0][2] = mfma_f16(ahi0, blo, acc[0][2]);
                acc[0][2] = mfma_f16(alo0, blo, acc[0][2]);
                acc[1][2] = mfma_f16(ahi1, bhi, acc[1][2]);
                acc[1][2] = mfma_f16(alo1, bhi, acc[1][2]);
                acc[1][2] = mfma_f16(ahi1, blo, acc[1][2]);
                acc[1][2] = mfma_f16(alo1, blo, acc[1][2]);
            } else {
                const size_t woff = (size_t)((12 + q) * 16 + lrow) * 128 + s * 32 + lk;
                s16x8 bhi = *reinterpret_cast<const s16x8*>(Wphi + woff);
                s16x8 blo = *reinterpret_cast<const s16x8*>(Wplo + woff);
                acc[0][3] = mfma_f16(ahi0, bhi, acc[0][3]);
                acc[0][3] = mfma_f16(alo0, bhi, acc[0][3]);
                acc[0][3] = mfma_f16(ahi0, blo, acc[0][3]);
                acc[0][3] = mfma_f16(alo0, blo, acc[0][3]);
                acc[1][3] = mfma_f16(ahi1, bhi, acc[1][3]);
                acc[1][3] = mfma_f16(alo1, bhi, acc[1][3]);
                acc[1][3] = mfma_f16(ahi1, blo, acc[1][3]);
                acc[1][3] = mfma_f16(alo1, blo, acc[1][3]);
            }
        }

        // per-pass epilogue (reads old h only; writes deferred)
        const int j = 16 * q + c;
        const float bihr = b_ih[j], bihz = b_ih[64 + j], bihn = b_ih[128 + j];
        const float bhhr = b_hh[j], bhhz = b_hh[64 + j], bhhn = b_hh[128 + j];
#pragma unroll
        for (int g = 0; g < 2; ++g) {
#pragma unroll
            for (int r = 0; r < 4; ++r) {
                int m = base + g * 16 + quarter * 4 + r;
                float rv = acc[g][0][r] + bihr + bhhr;
                float zv = acc[g][1][r] + bihz + bhhz;
                float iv = acc[g][2][r] + bihn;
                float hv = acc[g][3][r] + bhhn;
                rv = 1.f / (1.f + __expf(-rv));
                zv = 1.f / (1.f + __expf(-zv));
                float x2 = iv + rv * hv;
                float nn = 1.f - 2.f / (__expf(2.f * x2) + 1.f);  // tanh, inf-safe
                float hold = 0.f;
                if (m < n_nodes) hold = unpackhl(Xpk[(size_t)m * 128 + 64 + j]);
                pend[g][q][r] = (1.f - zv) * nn + zv * hold;
            }
        }
    }

    // deferred writes (all A-frag / hold reads complete)
#pragma unroll
    for (int g = 0; g < 2; ++g)
#pragma unroll
        for (int q = 0; q < 4; ++q)
#pragma unroll
            for (int r = 0; r < 4; ++r) {
                int m = base + g * 16 + quarter * 4 + r;
                if (m < n_nodes) {
                    int j = 16 * q + c;
                    Xpk[(size_t)m * 128 + 64 + j] = packhl(pend[g][q][r]);
                }
            }
}

// ---------------------------------------------------------------------------
// out = softmax(h @ w2.T + b2); h read from packed Xpk h-half
// ---------------------------------------------------------------------------
__global__ __launch_bounds__(256) void k_out(
    const u32* __restrict__ Xpk, const float* __restrict__ w2,
    const float* __restrict__ b2, float* __restrict__ out, int n_nodes)
{
    const int tid = threadIdx.x, lane = tid & 63;
    float wreg[64];
    float bias = 0.f;
    if (lane < NCLASS) {
#pragma unroll
        for (int k = 0; k < 64; k += 4) {
            float4 v = *reinterpret_cast<const float4*>(&w2[lane * HID + k]);
            wreg[k] = v.x; wreg[k + 1] = v.y; wreg[k + 2] = v.z; wreg[k + 3] = v.w;
        }
        bias = b2[lane];
    } else {
#pragma unroll
        for (int k = 0; k < 64; ++k) wreg[k] = 0.f;
    }
    int wid    = (blockIdx.x * blockDim.x + tid) >> 6;
    int nwaves = (gridDim.x * blockDim.x) >> 6;
    for (int node = wid; node < n_nodes; node += nwaves) {
        const uint4* p4 = reinterpret_cast<const uint4*>(Xpk + (size_t)node * 128 + 64);
        float a0 = bias, a1 = 0.f, a2 = 0.f, a3 = 0.f;
#pragma unroll
        for (int kq = 0; kq < 16; ++kq) {
            uint4 v = p4[kq];
            a0 = fmaf(unpackhl(v.x), wreg[4 * kq + 0], a0);
            a1 = fmaf(unpackhl(v.y), wreg[4 * kq + 1], a1);
            a2 = fmaf(unpackhl(v.z), wreg[4 * kq + 2], a2);
            a3 = fmaf(unpackhl(v.w), wreg[4 * kq + 3], a3);
        }
        float lg = (lane < NCLASS) ? (a0 + a1) + (a2 + a3) : -INFINITY;
        float m = lg;
#pragma unroll
        for (int off = 32; off > 0; off >>= 1) m = fmaxf(m, __shfl_xor(m, off, 64));
        float p = (lane < NCLASS) ? __expf(lg - m) : 0.f;
        float s = p;
#pragma unroll
        for (int off = 32; off > 0; off >>= 1) s += __shfl_xor(s, off, 64);
        if (lane < NCLASS) out[(size_t)node * NCLASS + lane] = p / s;
    }
}

// ---------------------------------------------------------------------------
extern "C" void kernel_launch(void* const* d_in, const int* in_sizes, int n_in,
                              void* d_out, int out_size, void* d_ws, size_t ws_size,
                              hipStream_t stream)
{
    const float* x    = (const float*)d_in[0];
    const int*   ei   = (const int*)d_in[1];    // int32 per harness contract
    const float* w1   = (const float*)d_in[2];
    const float* b1   = (const float*)d_in[3];
    const float* gg_w = (const float*)d_in[4];
    const float* w_ih = (const float*)d_in[5];
    const float* w_hh = (const float*)d_in[6];
    const float* b_ih = (const float*)d_in[7];
    const float* b_hh = (const float*)d_in[8];
    const float* w2   = (const float*)d_in[9];
    const float* b2   = (const float*)d_in[10];
    float*       out  = (float*)d_out;

    const int n = in_sizes[0] / NFEAT;   // 200000
    const int E = in_sizes[1] / 2;       // 1200000

    // workspace carve (~110 MB, proven envelope), 256-B aligned slots
    char* ws0 = (char*)d_ws;
    char* ws  = ws0;
    auto carve = [&](size_t bytes) {
        char* p = ws;
        ws += (bytes + 255) & ~(size_t)255;
        return p;
    };
    u32*   Xpk     = (u32*)carve((size_t)n * 128 * 4);               // 102.4 MB
    float* Wic     = (float*)carve((size_t)NUM_LAYERS * 192 * 64 * 4);
    u16*   Wphi    = (u16*)carve((size_t)NUM_LAYERS * 256 * 128 * 2);
    u16*   Wplo    = (u16*)carve((size_t)NUM_LAYERS * 256 * 128 * 2);
    int*   row_ptr = (int*)carve((size_t)(n + 1) * 4);
    int*   col_src = (int*)carve((size_t)E * 4);
    int*   cnt     = (int*)carve((size_t)n * 4);
    int*   cursor  = (int*)carve((size_t)n * 4);
    int*   btot    = (int*)carve(8192);

    const int nb = (n + SCAN_C - 1) / SCAN_C;

    hipMemsetAsync(cnt, 0, (size_t)n * 4, stream);
    k_wic<<<(NUM_LAYERS * 192 * 64 + 255) / 256, 256, 0, stream>>>(gg_w, w_ih, Wic);
    k_wpack<<<(NUM_LAYERS * 256 * 128 + 255) / 256, 256, 0, stream>>>(Wic, w_hh, Wphi, Wplo);
    k_lin1<<<2048, 256, 0, stream>>>(x, w1, b1, Xpk, n);
    k_hist<<<(E + 255) / 256, 256, 0, stream>>>(ei, cnt, E);
    k_scan1<<<nb, 512, 0, stream>>>(cnt, btot, n);
    k_scan2<<<1, 1024, 0, stream>>>(btot, nb);
    k_scan3<<<nb, 512, 0, stream>>>(cnt, btot, row_ptr, cursor, n);
    k_fill<<<(E + 255) / 256, 256, 0, stream>>>(ei, cursor, col_src, E);

    const int gblocks = (n + 127) / 128;  // 1563
    for (int l = 0; l < NUM_LAYERS; ++l) {
        k_agg2<<<2048, 256, 0, stream>>>(Xpk, row_ptr, col_src, n);
        k_gru9<<<gblocks, 256, 0, stream>>>(Xpk,
                                            Wphi + (size_t)l * 256 * 128,
                                            Wplo + (size_t)l * 256 * 128,
                                            b_ih, b_hh, n);
    }
    k_out<<<2048, 256, 0, stream>>>(Xpk, w2, b2, out, n);
}